// Round 14
// baseline (302.226 us; speedup 1.0000x reference)
//
#include <hip/hip_runtime.h>

// ---------------------------------------------------------------------------
// MultiHeadedAttention: B=4, S=2048, D=1024, H=16, DK=64
// out = ( softmax( mask_fill( (XqWq^T+bq)(XkWk^T+bk)^T / 8 ) ) (XvWv^T+bv) ) Wo^T + bo
// bf16 MFMA everywhere, f32 accum.
// R14: mask bit-pack overlapped with gemm_qkv — 65536 SINGLE-SHOT micro-
// blocks (one load+ballot+store each, no serial chain) appended after the
// 1536 GEMM blocks in a 1-D grid. They dispatch as GEMM blocks retire,
// consuming spare HBM BW (~2 TB/s) under GEMM compute. This differs from
// R10's failure (512 blocks x 128 SERIAL ballot rounds squatting CU slots).
// prep = converts only (164 MB ~= 26 us at HBM ceiling).
// KNOWN-FREE: attn SQ_LDS_BANK_CONFLICT = 4/b128-read = inherent 2-way
// aliasing (m136: free; R7 proved chasing it regresses).
// XCD map: XCD = linear_block_id % 8 — co-XCD sharers congruent mod 8
// (R8/R9). attn grid (64,16): bh%8 keys heads. gemm 1-D: bid%8 = M-tile%8.
// R3: no __launch_bounds__ min-waves beyond natural VGPR step.
// R12: split-KV/more-waves does not fix dependency-bound loops.
// ---------------------------------------------------------------------------

typedef __attribute__((ext_vector_type(8))) short bf16x8;    // 4 VGPRs: MFMA A/B frag
typedef __attribute__((ext_vector_type(4))) float f32x4;     // 16x16 C/D frag
typedef __attribute__((ext_vector_type(16))) float f32x16;   // 32x32 C/D frag
typedef __attribute__((ext_vector_type(4))) unsigned short us4;
typedef unsigned long long u64;
typedef unsigned short u16;
typedef unsigned int u32;

#define DEV static __device__ __forceinline__

template <int N> struct IC { static constexpr int v = N; };

DEV u16 f2bf(float f) {                     // RNE f32 -> bf16
  union { float f; unsigned u; } v; v.f = f;
  return (u16)((v.u + 0x7fffu + ((v.u >> 16) & 1u)) >> 16);
}

DEV u32 cvtpk(float lo, float hi) {         // HW RNE pack: [15:0]=bf16(lo),[31:16]=bf16(hi)
  u32 r;
  asm("v_cvt_pk_bf16_f32 %0, %1, %2" : "=v"(r) : "v"(lo), "v"(hi));
  return r;
}

// v_permlane32_swap_b32 x, y:  x' = [x_lo32 | y_lo32], y' = [x_hi32 | y_hi32]
DEV void plswap(u32& x, u32& y) {
  asm("v_permlane32_swap_b32 %0, %1" : "+v"(x), "+v"(y));
}

// raw v_exp_f32 (2^x): OCML exp2f adds range handling we don't need
DEV float fexp2(float x) {
#if __has_builtin(__builtin_amdgcn_exp2f)
  return __builtin_amdgcn_exp2f(x);
#else
  float r;
  asm volatile("v_exp_f32 %0, %1\n\ts_nop 1" : "=v"(r) : "v"(x));
  return r;
#endif
}

DEV int sbfe1(u32 w, int pos) {             // sign-extended 1-bit field: 0 or -1
#if __has_builtin(__builtin_amdgcn_sbfe)
  return __builtin_amdgcn_sbfe((int)w, pos, 1);
#else
  return ((int)(w << (31 - pos))) >> 31;
#endif
}

DEV float fmask(float s, int m) {           // s if m==-1 else 0.0f (bitwise and)
  union { float f; int i; } u; u.f = s; u.i &= m; return u.f;
}

DEV void gl16(const u16* g, u16* l) {       // async global->LDS, 16B/lane
  __builtin_amdgcn_global_load_lds(
      (const __attribute__((address_space(1))) unsigned int*)g,
      (__attribute__((address_space(3))) unsigned int*)l, 16, 0, 0);
}

// XOR swizzle (involution): spreads 16B slots across banks. Used on BOTH the
// pre-swizzled global source (staging) and the ds_read side (rule #21).
DEV int swz(int row, int slot) { return slot ^ (row & 7); }

// ---------------------------------------------------------------------------
// prep: f32 -> bf16 converts only (mask pack rides in gemm_qkv tail blocks)
// ---------------------------------------------------------------------------
__global__ void prep_kernel(const float4* __restrict__ q, const float4* __restrict__ k,
                            const float4* __restrict__ v, const float4* __restrict__ wq,
                            const float4* __restrict__ wk, const float4* __restrict__ wv,
                            const float4* __restrict__ wo,
                            us4* __restrict__ xq, us4* __restrict__ xk, us4* __restrict__ xv,
                            us4* __restrict__ owq, us4* __restrict__ owk,
                            us4* __restrict__ owv, us4* __restrict__ owo) {
  const int bid = blockIdx.x;
  const float4* src; us4* dst; int base;
  if (bid < 8192)       { src = q;  dst = xq;  base = 0; }
  else if (bid < 16384) { src = k;  dst = xk;  base = 8192; }
  else if (bid < 24576) { src = v;  dst = xv;  base = 16384; }
  else if (bid < 25600) { src = wq; dst = owq; base = 24576; }
  else if (bid < 26624) { src = wk; dst = owk; base = 25600; }
  else if (bid < 27648) { src = wv; dst = owv; base = 26624; }
  else                  { src = wo; dst = owo; base = 27648; }
  const int i = (bid - base) * 256 + threadIdx.x;
  const float4 t = src[i];
  us4 r = {f2bf(t.x), f2bf(t.y), f2bf(t.z), f2bf(t.w)};
  dst[i] = r;
}

// ---------------------------------------------------------------------------
// GEMM body: D[pr][qr] = sum_k P[pr][k]*Q[qr][k]  (+bias), both K-major.
// 128x128 tile, BK=64, 4 waves (2x2), wave=64x64 out = 4x4 frags of 16x16x32.
// MODE 0: out bf16 [b,h,s,dk] ; MODE 1: out bf16 [b,h,dk,s] (V^T) ;
// MODE 2: out f32 [m,n] ; MODE 3: like 0 but scaled by log2(e)/8 (Q proj).
// ---------------------------------------------------------------------------
template <int MODE>
DEV void gemm_body(const u16* __restrict__ P, const u16* __restrict__ Q,
                   const float* __restrict__ bias, void* __restrict__ outp,
                   int pr0, int qr0, u16* lsP, u16* lsQ) {
  constexpr int K = 1024;
  const int tid = threadIdx.x;
  const int w = tid >> 6, lane = tid & 63;
  const int wm = w >> 1, wn = w & 1;
  const int lo = lane & 15, hi = lane >> 4;
  const int srow = lane >> 3, sslot = lane & 7;   // staging: 8 rows x 8 slots / 1KB chunk

  f32x4 acc[4][4];
#pragma unroll
  for (int i = 0; i < 4; ++i)
#pragma unroll
    for (int j = 0; j < 4; ++j) acc[i][j] = (f32x4){0.f, 0.f, 0.f, 0.f};

  for (int kt = 0; kt < K; kt += 64) {
#pragma unroll
    for (int j = 0; j < 4; ++j) {
      const int c = w * 4 + j;
      const int row = c * 8 + srow;
      const int gs = swz(row, sslot);           // pre-swizzled global source
      gl16(P + (pr0 + row) * K + kt + gs * 8, &lsP[c * 512]);
      gl16(Q + (qr0 + row) * K + kt + gs * 8, &lsQ[c * 512]);
    }
    __syncthreads();   // drains vmcnt before barrier
#pragma unroll
    for (int kk = 0; kk < 2; ++kk) {
      bf16x8 af[4], bfr[4];
#pragma unroll
      for (int mf = 0; mf < 4; ++mf) {
        const int r = wm * 64 + mf * 16 + lo;
        af[mf] = *(const bf16x8*)&lsP[r * 64 + swz(r, kk * 4 + hi) * 8];
      }
#pragma unroll
      for (int nf = 0; nf < 4; ++nf) {
        const int r = wn * 64 + nf * 16 + lo;
        bfr[nf] = *(const bf16x8*)&lsQ[r * 64 + swz(r, kk * 4 + hi) * 8];
      }
#pragma unroll
      for (int mf = 0; mf < 4; ++mf)
#pragma unroll
        for (int nf = 0; nf < 4; ++nf)
          acc[mf][nf] = __builtin_amdgcn_mfma_f32_16x16x32_bf16(af[mf], bfr[nf], acc[mf][nf], 0, 0, 0);
    }
    __syncthreads();
  }

#pragma unroll
  for (int mf = 0; mf < 4; ++mf) {
#pragma unroll
    for (int nf = 0; nf < 4; ++nf) {
#pragma unroll
      for (int i = 0; i < 4; ++i) {
        const int gm = pr0 + wm * 64 + mf * 16 + hi * 4 + i;
        const int gn = qr0 + wn * 64 + nf * 16 + lo;
        float val = acc[mf][nf][i];
        if constexpr (MODE == 0 || MODE == 3) {  // [b,h,s,dk] bf16 (K / scaled Q)
          val += bias[gn];
          if constexpr (MODE == 3) val *= 0.18033688011112042f;  // log2(e)/8
          const int b = gm >> 11, s = gm & 2047, h = gn >> 6, dk = gn & 63;
          ((u16*)outp)[(((b * 16 + h) * 2048 + s) * 64) + dk] = f2bf(val);
        } else if constexpr (MODE == 1) { // [b,h,dk,s] bf16 (V^T)
          val += bias[gm];
          const int h = gm >> 6, dk = gm & 63, b = gn >> 11, s = gn & 2047;
          ((u16*)outp)[(((b * 16 + h) * 64 + dk) * 2048) + s] = f2bf(val);
        } else {                          // f32 [m,n]
          val += bias[gn];
          ((float*)outp)[(size_t)gm * 1024 + gn] = val;
        }
      }
    }
  }
}

// 1-D grid: bid < 1536 -> GEMM blocks (mt=bid&63 [XCD key], nt=(bid>>6)&7,
// z=bid>>9: 0=scaled Q proj, 1=K proj, 2=V proj writing V^T);
// bid >= 1536 -> 65536 single-shot mask micro-blocks (load+ballot+store,
// no serial chain; dispatch after GEMM blocks, fill spare BW/slots).
__launch_bounds__(256)
__global__ void gemm_qkv(const u16* __restrict__ xq, const u16* __restrict__ xk,
                         const u16* __restrict__ xv, const u16* __restrict__ wq,
                         const u16* __restrict__ wk, const u16* __restrict__ wv,
                         const float* __restrict__ bq, const float* __restrict__ bk,
                         const float* __restrict__ bv, u16* __restrict__ q16,
                         u16* __restrict__ k16, u16* __restrict__ vt16,
                         const int* __restrict__ mask, u64* __restrict__ bits) {
  __shared__ u16 lsP[128 * 64];
  __shared__ u16 lsQ[128 * 64];
  const int bid = blockIdx.x;
  if (bid >= 1536) {                       // mask micro-block: one shot, exit
    const int i = (bid - 1536) * 256 + threadIdx.x;
    const u64 bm = __ballot(mask[i] != 0);
    if ((threadIdx.x & 63) == 0) bits[i >> 6] = bm;
    return;
  }
  const int mt = bid & 63, nt = (bid >> 6) & 7, z = bid >> 9;
  if (z == 0)      gemm_body<3>(xq, wq, bq, q16,  mt * 128, nt * 128, lsP, lsQ);
  else if (z == 1) gemm_body<0>(xk, wk, bk, k16,  mt * 128, nt * 128, lsP, lsQ);
  else             gemm_body<1>(wv, xv, bv, vt16, nt * 128, mt * 128, lsP, lsQ);
}

// grid (64, 8): x = M-tile (XCD key), y = N-tile
__launch_bounds__(256)
__global__ void gemm_out(const u16* __restrict__ P, const u16* __restrict__ Q,
                         const float* __restrict__ bias, float* __restrict__ outp) {
  __shared__ u16 lsP[128 * 64];
  __shared__ u16 lsQ[128 * 64];
  gemm_body<2>(P, Q, bias, outp, blockIdx.x * 128, blockIdx.y * 128, lsP, lsQ);
}

// ---------------------------------------------------------------------------
// Flash attention. grid=(B*H, S/128): linear id = bh + 64*qt -> XCD = bh%8,
// so each XCD owns 8 whole heads (per-head K/V fetched by one XCD only).
// 256 thr = 4 waves, wave owns 32 q-rows. 32x32x16 MFMA, swapped operands:
// S' = mfma(K,Qs), Qs pre-scaled log2(e)/8; p = exp2(S' & mask) (masked ->
// 1.0 == TINY fill; numerator scale-invariant). P in regs via cvt_pk +
// v_permlane32_swap; O^T = mfma(V^T, P).
// Address-free body (R13): t-loop unrolled x2, constexpr buffer selection
// (lsK0/lsK1/lsV0/lsV1), hoisted per-lane offsets idx[4], walked stage ptrs.
// ---------------------------------------------------------------------------
__launch_bounds__(256, 4)
__global__ void attn_kernel(const u16* __restrict__ q16, const u16* __restrict__ k16,
                            const u16* __restrict__ vt16, const u64* __restrict__ mb,
                            u16* __restrict__ x16) {
  __shared__ u16 lsK0[64 * 64], lsK1[64 * 64];   // [kv 64][dk 64] swizzled, 8KB each
  __shared__ u16 lsV0[64 * 64], lsV1[64 * 64];   // [dk 64][kv 64] swizzled, 8KB each
  const int bh = blockIdx.x;
  const int b = bh >> 4, h = bh & 15;
  const int w = threadIdx.x >> 6, lane = threadIdx.x & 63;
  const int l5 = lane & 31, h1 = lane >> 5, l7 = l5 & 7;
  const int h4 = h1 * 4;
  const int q0 = blockIdx.y * 128 + w * 32;
  const u16* qbase = q16 + (size_t)bh * 2048 * 64;
  const u16* kbase = k16 + (size_t)bh * 2048 * 64;
  const u16* vbase = vt16 + (size_t)bh * 64 * 2048;
  const u64* mp = mb + ((size_t)b * 2048 + q0 + l5) * 32;   // this lane's q-row

  // per-lane constant LDS read offsets (u16 units); f/db add 2048 via imm
  int idx[4];
#pragma unroll
  for (int s4 = 0; s4 < 4; ++s4)
    idx[s4] = l5 * 64 + (((s4 * 2 + h1) ^ l7) * 8);

  // staging geometry: chunks cA=2w, cB=2w+1; rows rowA/rowB; both share gs
  const int srow = lane >> 3, sslot = lane & 7;
  const int gs = (sslot ^ srow) * 8;             // row&7 == srow for both chunks
  const int rowA = w * 16 + srow, rowB = rowA + 8;
  const int dA = w * 1024, dB = w * 1024 + 512;  // LDS chunk dests (u16 units)
  const u16* kgA = kbase + rowA * 64 + gs;       // walked per tile: +4096
  const u16* kgB = kbase + rowB * 64 + gs;
  const u16* vgA = vbase + rowA * 2048 + gs;     // walked per tile: +64
  const u16* vgB = vbase + rowB * 2048 + gs;

  const f32x16 z16 = (f32x16)(0.f);

  // Q frags (B-operand): lane holds Qs[q0+l5][step*16 + h1*8 .. +8]
  bf16x8 qf[4];
#pragma unroll
  for (int step = 0; step < 4; ++step)
    qf[step] = *(const bf16x8*)&qbase[(q0 + l5) * 64 + step * 16 + h1 * 8];

  f32x16 acc[2];                                 // O^T frags: d-blocks 0,1
  acc[0] = z16; acc[1] = z16;
  float lp0 = 0.f, lp1 = 0.f, lp2 = 0.f, lp3 = 0.f;  // 4-way split row-sum chains

  // prologue: stage tile 0 into buf 0, then advance pointers to tile 1
  gl16(kgA, &lsK0[dA]); gl16(kgB, &lsK0[dB]);
  gl16(vgA, &lsV0[dA]); gl16(vgB, &lsV0[dB]);
  kgA += 4096; kgB += 4096; vgA += 64; vgB += 64;

  auto body = [&](auto curTag, int t) {
    constexpr int CUR = decltype(curTag)::v;
    const u16* lskR = CUR ? lsK1 : lsK0;
    const u16* lsvR = CUR ? lsV1 : lsV0;
    u16* lskW = CUR ? lsK0 : lsK1;
    u16* lsvW = CUR ? lsV0 : lsV1;

    __syncthreads();   // buf[CUR] staged (vmcnt drain); all waves past body t-1

    if (t < 31) {      // stage tile t+1 into the other buffer
      gl16(kgA, &lskW[dA]); gl16(kgB, &lskW[dB]);
      gl16(vgA, &lsvW[dA]); gl16(vgB, &lsvW[dB]);
      kgA += 4096; kgB += 4096; vgA += 64; vgB += 64;
    }

    const u64 mw = *mp; ++mp;                    // 64 mask bits (q=l5, this tile)

    // S' = mfma(K, Qs): frag f covers kv = f*32.. ; lane holds q=l5,
    // kv = f*32 + (r&3) + 8*(r>>2) + 4*h1 per reg r.
    f32x16 s2[2];
    __builtin_amdgcn_s_setprio(1);
#pragma unroll
    for (int f = 0; f < 2; ++f) {
      f32x16 sv = z16;
#pragma unroll
      for (int step = 0; step < 4; ++step) {
        const bf16x8 kf = *(const bf16x8*)&lskR[idx[step] + f * 2048];
        sv = __builtin_amdgcn_mfma_f32_32x32x16_bf16(kf, qf[step], sv, 0, 0, 0);
      }
      s2[f] = sv;
    }
    __builtin_amdgcn_s_setprio(0);

    // softmax numerators p = exp2(S' & m)  (masked -> 1.0) + PV
#pragma unroll
    for (int f = 0; f < 2; ++f) {
      const u32 wf = ((f == 0) ? (u32)mw : (u32)(mw >> 32)) >> h4;
      float p[16];
#pragma unroll
      for (int r = 0; r < 16; ++r) {
        const int pos = (r & 3) + 8 * (r >> 2);
        const int m = sbfe1(wf, pos);            // 0 or -1
        p[r] = fexp2(fmask(s2[f][r], m));
      }
      lp0 += (p[0] + p[4]) + (p[8] + p[12]);
      lp1 += (p[1] + p[5]) + (p[9] + p[13]);
      lp2 += (p[2] + p[6]) + (p[10] + p[14]);
      lp3 += (p[3] + p[7]) + (p[11] + p[15]);
      u32 pk[8];
#pragma unroll
      for (int i = 0; i < 4; ++i) {
        pk[2 * i]     = cvtpk(p[4 * i],     p[4 * i + 1]);
        pk[2 * i + 1] = cvtpk(p[4 * i + 2], p[4 * i + 3]);
      }
      // exchange quads across lane halves: each half gets its 8-contiguous kv run
      plswap(pk[0], pk[2]); plswap(pk[1], pk[3]);   // kv block f*32 + 0..15
      plswap(pk[4], pk[6]); plswap(pk[5], pk[7]);   // kv block f*32 + 16..31

#pragma unroll
      for (int mm = 0; mm < 2; ++mm) {
        const int m = f * 2 + mm;                 // kv 16-block index
        union { u32 u[4]; bf16x8 v; } pu;
        pu.u[0] = pk[4 * mm]; pu.u[1] = pk[4 * mm + 1];
        pu.u[2] = pk[4 * mm + 2]; pu.u[3] = pk[4 * mm + 3];
        __builtin_amdgcn_s_setprio(1);
#pragma unroll
        for (int db = 0; db < 2; ++db) {
          const bf16x8 vf = *(const bf16x8*)&lsvR[idx[m] + db * 2048];
          acc[db] = __builtin_amdgcn_mfma_f32_32x32x16_bf16(vf, pu.v, acc[db], 0, 0, 0);
        }
        __builtin_amdgcn_s_setprio(0);
      }
    }
  };

  for (int tt = 0; tt < 16; ++tt) {
    body(IC<0>{}, 2 * tt);
    body(IC<1>{}, 2 * tt + 1);
  }

  // row sum = own half + partner half (lane l5 <-> l5+32), one rcp per lane
  const float lpart = (lp0 + lp1) + (lp2 + lp3);
  const float tot = lpart + __shfl_xor(lpart, 32, 64);
  const float inv = 1.0f / tot;

  // write O^T: lane (l5,h1) holds O[q=q0+l5][d = db*32 + (r&3)+8*(r>>2)+4*h1]
  u16* orow = x16 + ((size_t)b * 2048 + q0 + l5) * 1024 + h * 64;
#pragma unroll
  for (int db = 0; db < 2; ++db)
#pragma unroll
    for (int r = 0; r < 16; r += 2) {
      const int d = db * 32 + (r & 3) + 8 * (r >> 2) + h4;
      *(u32*)&orow[d] = cvtpk(acc[db][r] * inv, acc[db][r + 1] * inv);
    }
}

// ---------------------------------------------------------------------------
extern "C" void kernel_launch(void* const* d_in, const int* in_sizes, int n_in,
                              void* d_out, int out_size, void* d_ws, size_t ws_size,
                              hipStream_t stream) {
  const float* query = (const float*)d_in[0];
  const float* key   = (const float*)d_in[1];
  const float* value = (const float*)d_in[2];
  const int*   mask  = (const int*)d_in[3];
  const float* Wq = (const float*)d_in[4];
  const float* bq = (const float*)d_in[5];
  const float* Wk = (const float*)d_in[6];
  const float* bk = (const float*)d_in[7];
  const float* Wv = (const float*)d_in[8];
  const float* bv = (const float*)d_in[9];
  const float* Wo = (const float*)d_in[10];
  const float* bo = (const float*)d_in[11];

  char* ws = (char*)d_ws;
  const size_t MB = 1024 * 1024;
  u16* xq   = (u16*)(ws + 0);        // 16MB  [B*S,D] bf16 (later reused as x16)
  u16* xk   = (u16*)(ws + 16 * MB);  // 16MB
  u16* xv   = (u16*)(ws + 32 * MB);  // 16MB
  u16* wq16 = (u16*)(ws + 48 * MB);  // 2MB
  u16* wk16 = (u16*)(ws + 50 * MB);
  u16* wv16 = (u16*)(ws + 52 * MB);
  u16* wo16 = (u16*)(ws + 54 * MB);
  u16* q16  = (u16*)(ws + 56 * MB);  // 16MB [b,h,s,dk] (pre-scaled by log2e/8)
  u16* k16  = (u16*)(ws + 72 * MB);  // 16MB [b,h,s,dk]
  u16* vt16 = (u16*)(ws + 88 * MB);  // 16MB [b,h,dk,s]
  u64* mbits = (u64*)(ws + 104 * MB);// 2MB
  u16* x16  = xq;                    // alias: xq dead before attn writes

  prep_kernel<<<28672, 256, 0, stream>>>(
      (const float4*)query, (const float4*)key, (const float4*)value,
      (const float4*)Wq, (const float4*)Wk, (const float4*)Wv, (const float4*)Wo,
      (us4*)xq, (us4*)xk, (us4*)xv,
      (us4*)wq16, (us4*)wk16, (us4*)wv16, (us4*)wo16);

  gemm_qkv<<<1536 + 65536, 256, 0, stream>>>(xq, xk, xv, wq16, wk16, wv16,
                                             bq, bk, bv, q16, k16, vt16,
                                             mask, mbits);

  attn_kernel<<<dim3(64, 16), 256, 0, stream>>>(q16, k16, vt16, mbits, x16);

  gemm_out<<<dim3(64, 8), 256, 0, stream>>>(x16, wo16, bo, (float*)d_out);
}

// Round 15
// 221.271 us; speedup vs baseline: 1.3659x; 1.3659x over previous
//
#include <hip/hip_runtime.h>

// ---------------------------------------------------------------------------
// MultiHeadedAttention: B=4, S=2048, D=1024, H=16, DK=64
// out = ( softmax( mask_fill( (XqWq^T+bq)(XkWk^T+bk)^T / 8 ) ) (XvWv^T+bv) ) Wo^T + bo
// bf16 MFMA everywhere, f32 accum.
// R15: REVERT R14 (mask micro-blocks in gemm_qkv: slot/L2 competition,
// gemm_qkv 65->175us). Lesson (final): heterogeneous block fusion into a
// compute kernel fails for BOTH serial-chain passengers (R10) AND
// slot/L2-competing streams (R14) — bulk memory work stays in dedicated
// kernels. This round: R13 structure + mask pack with 4 INDEPENDENT
// rounds/block (4x memory-level parallelism inside the dedicated prep).
// KNOWN-FREE: attn SQ_LDS_BANK_CONFLICT = 4/b128-read = inherent 2-way
// aliasing (m136: free; R7 proved chasing it regresses).
// XCD map: XCD = linear_block_id % 8 — co-XCD sharers congruent mod 8
// (R8/R9). attn grid (64,16): bh%8 keys heads. GEMMs grid (64,8,*):
// M-tile%8 keys XCD -> A-panels XCD-private.
// R3: no __launch_bounds__ min-waves beyond natural VGPR step.
// R12: split-KV/more-waves does not fix dependency-bound loops.
// ---------------------------------------------------------------------------

typedef __attribute__((ext_vector_type(8))) short bf16x8;    // 4 VGPRs: MFMA A/B frag
typedef __attribute__((ext_vector_type(4))) float f32x4;     // 16x16 C/D frag
typedef __attribute__((ext_vector_type(16))) float f32x16;   // 32x32 C/D frag
typedef __attribute__((ext_vector_type(4))) unsigned short us4;
typedef unsigned long long u64;
typedef unsigned short u16;
typedef unsigned int u32;

#define DEV static __device__ __forceinline__

template <int N> struct IC { static constexpr int v = N; };

DEV u16 f2bf(float f) {                     // RNE f32 -> bf16
  union { float f; unsigned u; } v; v.f = f;
  return (u16)((v.u + 0x7fffu + ((v.u >> 16) & 1u)) >> 16);
}

DEV u32 cvtpk(float lo, float hi) {         // HW RNE pack: [15:0]=bf16(lo),[31:16]=bf16(hi)
  u32 r;
  asm("v_cvt_pk_bf16_f32 %0, %1, %2" : "=v"(r) : "v"(lo), "v"(hi));
  return r;
}

// v_permlane32_swap_b32 x, y:  x' = [x_lo32 | y_lo32], y' = [x_hi32 | y_hi32]
DEV void plswap(u32& x, u32& y) {
  asm("v_permlane32_swap_b32 %0, %1" : "+v"(x), "+v"(y));
}

// raw v_exp_f32 (2^x): OCML exp2f adds range handling we don't need
DEV float fexp2(float x) {
#if __has_builtin(__builtin_amdgcn_exp2f)
  return __builtin_amdgcn_exp2f(x);
#else
  float r;
  asm volatile("v_exp_f32 %0, %1\n\ts_nop 1" : "=v"(r) : "v"(x));
  return r;
#endif
}

DEV int sbfe1(u32 w, int pos) {             // sign-extended 1-bit field: 0 or -1
#if __has_builtin(__builtin_amdgcn_sbfe)
  return __builtin_amdgcn_sbfe((int)w, pos, 1);
#else
  return ((int)(w << (31 - pos))) >> 31;
#endif
}

DEV float fmask(float s, int m) {           // s if m==-1 else 0.0f (bitwise and)
  union { float f; int i; } u; u.f = s; u.i &= m; return u.f;
}

DEV void gl16(const u16* g, u16* l) {       // async global->LDS, 16B/lane
  __builtin_amdgcn_global_load_lds(
      (const __attribute__((address_space(1))) unsigned int*)g,
      (__attribute__((address_space(3))) unsigned int*)l, 16, 0, 0);
}

// XOR swizzle (involution): spreads 16B slots across banks. Used on BOTH the
// pre-swizzled global source (staging) and the ds_read side (rule #21).
DEV int swz(int row, int slot) { return slot ^ (row & 7); }

// ---------------------------------------------------------------------------
// Fused prep: f32->bf16 converts (q/k/v + 4 weights) and mask bit-pack.
// Mask region: 16384 blocks x 4 INDEPENDENT rounds (loads issue together ->
// 4x per-wave MLP; no serial dependency chain).
// ---------------------------------------------------------------------------
__global__ void prep_kernel(const float4* __restrict__ q, const float4* __restrict__ k,
                            const float4* __restrict__ v, const float4* __restrict__ wq,
                            const float4* __restrict__ wk, const float4* __restrict__ wv,
                            const float4* __restrict__ wo, const int* __restrict__ mask,
                            us4* __restrict__ xq, us4* __restrict__ xk, us4* __restrict__ xv,
                            us4* __restrict__ owq, us4* __restrict__ owk,
                            us4* __restrict__ owv, us4* __restrict__ owo,
                            u64* __restrict__ bits) {
  const int bid = blockIdx.x;
  if (bid < 28672) {                       // convert regions
    const float4* src; us4* dst; int base;
    if (bid < 8192)       { src = q;  dst = xq;  base = 0; }
    else if (bid < 16384) { src = k;  dst = xk;  base = 8192; }
    else if (bid < 24576) { src = v;  dst = xv;  base = 16384; }
    else if (bid < 25600) { src = wq; dst = owq; base = 24576; }
    else if (bid < 26624) { src = wk; dst = owk; base = 25600; }
    else if (bid < 27648) { src = wv; dst = owv; base = 26624; }
    else                  { src = wo; dst = owo; base = 27648; }
    const int i = (bid - base) * 256 + threadIdx.x;
    const float4 t = src[i];
    us4 r = {f2bf(t.x), f2bf(t.y), f2bf(t.z), f2bf(t.w)};
    dst[i] = r;
  } else {                                 // mask pack: 16384 blocks x 4 rounds
    const int base = (bid - 28672) * 1024 + threadIdx.x;
    int mv[4];
#pragma unroll
    for (int kk = 0; kk < 4; ++kk) mv[kk] = mask[base + kk * 256];  // 4 loads in flight
#pragma unroll
    for (int kk = 0; kk < 4; ++kk) {
      const u64 bm = __ballot(mv[kk] != 0);
      if ((threadIdx.x & 63) == 0) bits[(base + kk * 256) >> 6] = bm;
    }
  }
}

// ---------------------------------------------------------------------------
// GEMM body: D[pr][qr] = sum_k P[pr][k]*Q[qr][k]  (+bias), both K-major.
// 128x128 tile, BK=64, 4 waves (2x2), wave=64x64 out = 4x4 frags of 16x16x32.
// MODE 0: out bf16 [b,h,s,dk] ; MODE 1: out bf16 [b,h,dk,s] (V^T) ;
// MODE 2: out f32 [m,n] ; MODE 3: like 0 but scaled by log2(e)/8 (Q proj).
// ---------------------------------------------------------------------------
template <int MODE>
DEV void gemm_body(const u16* __restrict__ P, const u16* __restrict__ Q,
                   const float* __restrict__ bias, void* __restrict__ outp,
                   int pr0, int qr0, u16* lsP, u16* lsQ) {
  constexpr int K = 1024;
  const int tid = threadIdx.x;
  const int w = tid >> 6, lane = tid & 63;
  const int wm = w >> 1, wn = w & 1;
  const int lo = lane & 15, hi = lane >> 4;
  const int srow = lane >> 3, sslot = lane & 7;   // staging: 8 rows x 8 slots / 1KB chunk

  f32x4 acc[4][4];
#pragma unroll
  for (int i = 0; i < 4; ++i)
#pragma unroll
    for (int j = 0; j < 4; ++j) acc[i][j] = (f32x4){0.f, 0.f, 0.f, 0.f};

  for (int kt = 0; kt < K; kt += 64) {
#pragma unroll
    for (int j = 0; j < 4; ++j) {
      const int c = w * 4 + j;
      const int row = c * 8 + srow;
      const int gs = swz(row, sslot);           // pre-swizzled global source
      gl16(P + (pr0 + row) * K + kt + gs * 8, &lsP[c * 512]);
      gl16(Q + (qr0 + row) * K + kt + gs * 8, &lsQ[c * 512]);
    }
    __syncthreads();   // drains vmcnt before barrier
#pragma unroll
    for (int kk = 0; kk < 2; ++kk) {
      bf16x8 af[4], bfr[4];
#pragma unroll
      for (int mf = 0; mf < 4; ++mf) {
        const int r = wm * 64 + mf * 16 + lo;
        af[mf] = *(const bf16x8*)&lsP[r * 64 + swz(r, kk * 4 + hi) * 8];
      }
#pragma unroll
      for (int nf = 0; nf < 4; ++nf) {
        const int r = wn * 64 + nf * 16 + lo;
        bfr[nf] = *(const bf16x8*)&lsQ[r * 64 + swz(r, kk * 4 + hi) * 8];
      }
#pragma unroll
      for (int mf = 0; mf < 4; ++mf)
#pragma unroll
        for (int nf = 0; nf < 4; ++nf)
          acc[mf][nf] = __builtin_amdgcn_mfma_f32_16x16x32_bf16(af[mf], bfr[nf], acc[mf][nf], 0, 0, 0);
    }
    __syncthreads();
  }

#pragma unroll
  for (int mf = 0; mf < 4; ++mf) {
#pragma unroll
    for (int nf = 0; nf < 4; ++nf) {
#pragma unroll
      for (int i = 0; i < 4; ++i) {
        const int gm = pr0 + wm * 64 + mf * 16 + hi * 4 + i;
        const int gn = qr0 + wn * 64 + nf * 16 + lo;
        float val = acc[mf][nf][i];
        if constexpr (MODE == 0 || MODE == 3) {  // [b,h,s,dk] bf16 (K / scaled Q)
          val += bias[gn];
          if constexpr (MODE == 3) val *= 0.18033688011112042f;  // log2(e)/8
          const int b = gm >> 11, s = gm & 2047, h = gn >> 6, dk = gn & 63;
          ((u16*)outp)[(((b * 16 + h) * 2048 + s) * 64) + dk] = f2bf(val);
        } else if constexpr (MODE == 1) { // [b,h,dk,s] bf16 (V^T)
          val += bias[gm];
          const int h = gm >> 6, dk = gm & 63, b = gn >> 11, s = gn & 2047;
          ((u16*)outp)[(((b * 16 + h) * 64 + dk) * 2048) + s] = f2bf(val);
        } else {                          // f32 [m,n]
          val += bias[gn];
          ((float*)outp)[(size_t)gm * 1024 + gn] = val;
        }
      }
    }
  }
}

// fused Q/K/V projections, grid (64, 8, 3): x = M-tile (XCD key: A-panels
// XCD-private, fetched once; 2MB B replicated per XCD), y = N-tile.
// z=0 -> scaled Q proj, z=1 -> K proj, z=2 -> V proj (writes V^T).
__launch_bounds__(256)
__global__ void gemm_qkv(const u16* __restrict__ xq, const u16* __restrict__ xk,
                         const u16* __restrict__ xv, const u16* __restrict__ wq,
                         const u16* __restrict__ wk, const u16* __restrict__ wv,
                         const float* __restrict__ bq, const float* __restrict__ bk,
                         const float* __restrict__ bv, u16* __restrict__ q16,
                         u16* __restrict__ k16, u16* __restrict__ vt16) {
  __shared__ u16 lsP[128 * 64];
  __shared__ u16 lsQ[128 * 64];
  const int z = blockIdx.z;
  if (z == 0)      gemm_body<3>(xq, wq, bq, q16,  blockIdx.x * 128, blockIdx.y * 128, lsP, lsQ);
  else if (z == 1) gemm_body<0>(xk, wk, bk, k16,  blockIdx.x * 128, blockIdx.y * 128, lsP, lsQ);
  else             gemm_body<1>(wv, xv, bv, vt16, blockIdx.y * 128, blockIdx.x * 128, lsP, lsQ);
}

// grid (64, 8): x = M-tile (XCD key), y = N-tile
__launch_bounds__(256)
__global__ void gemm_out(const u16* __restrict__ P, const u16* __restrict__ Q,
                         const float* __restrict__ bias, float* __restrict__ outp) {
  __shared__ u16 lsP[128 * 64];
  __shared__ u16 lsQ[128 * 64];
  gemm_body<2>(P, Q, bias, outp, blockIdx.x * 128, blockIdx.y * 128, lsP, lsQ);
}

// ---------------------------------------------------------------------------
// Flash attention. grid=(B*H, S/128): linear id = bh + 64*qt -> XCD = bh%8,
// so each XCD owns 8 whole heads (per-head K/V fetched by one XCD only).
// 256 thr = 4 waves, wave owns 32 q-rows. 32x32x16 MFMA, swapped operands:
// S' = mfma(K,Qs), Qs pre-scaled log2(e)/8; p = exp2(S' & mask) (masked ->
// 1.0 == TINY fill; numerator scale-invariant). P in regs via cvt_pk +
// v_permlane32_swap; O^T = mfma(V^T, P).
// Address-free body (R13): t-loop unrolled x2, constexpr buffer selection
// (lsK0/lsK1/lsV0/lsV1), hoisted per-lane offsets idx[4], walked stage ptrs.
// ---------------------------------------------------------------------------
__launch_bounds__(256, 4)
__global__ void attn_kernel(const u16* __restrict__ q16, const u16* __restrict__ k16,
                            const u16* __restrict__ vt16, const u64* __restrict__ mb,
                            u16* __restrict__ x16) {
  __shared__ u16 lsK0[64 * 64], lsK1[64 * 64];   // [kv 64][dk 64] swizzled, 8KB each
  __shared__ u16 lsV0[64 * 64], lsV1[64 * 64];   // [dk 64][kv 64] swizzled, 8KB each
  const int bh = blockIdx.x;
  const int b = bh >> 4, h = bh & 15;
  const int w = threadIdx.x >> 6, lane = threadIdx.x & 63;
  const int l5 = lane & 31, h1 = lane >> 5, l7 = l5 & 7;
  const int h4 = h1 * 4;
  const int q0 = blockIdx.y * 128 + w * 32;
  const u16* qbase = q16 + (size_t)bh * 2048 * 64;
  const u16* kbase = k16 + (size_t)bh * 2048 * 64;
  const u16* vbase = vt16 + (size_t)bh * 64 * 2048;
  const u64* mp = mb + ((size_t)b * 2048 + q0 + l5) * 32;   // this lane's q-row

  // per-lane constant LDS read offsets (u16 units); f/db add 2048 via imm
  int idx[4];
#pragma unroll
  for (int s4 = 0; s4 < 4; ++s4)
    idx[s4] = l5 * 64 + (((s4 * 2 + h1) ^ l7) * 8);

  // staging geometry: chunks cA=2w, cB=2w+1; rows rowA/rowB; both share gs
  const int srow = lane >> 3, sslot = lane & 7;
  const int gs = (sslot ^ srow) * 8;             // row&7 == srow for both chunks
  const int rowA = w * 16 + srow, rowB = rowA + 8;
  const int dA = w * 1024, dB = w * 1024 + 512;  // LDS chunk dests (u16 units)
  const u16* kgA = kbase + rowA * 64 + gs;       // walked per tile: +4096
  const u16* kgB = kbase + rowB * 64 + gs;
  const u16* vgA = vbase + rowA * 2048 + gs;     // walked per tile: +64
  const u16* vgB = vbase + rowB * 2048 + gs;

  const f32x16 z16 = (f32x16)(0.f);

  // Q frags (B-operand): lane holds Qs[q0+l5][step*16 + h1*8 .. +8]
  bf16x8 qf[4];
#pragma unroll
  for (int step = 0; step < 4; ++step)
    qf[step] = *(const bf16x8*)&qbase[(q0 + l5) * 64 + step * 16 + h1 * 8];

  f32x16 acc[2];                                 // O^T frags: d-blocks 0,1
  acc[0] = z16; acc[1] = z16;
  float lp0 = 0.f, lp1 = 0.f, lp2 = 0.f, lp3 = 0.f;  // 4-way split row-sum chains

  // prologue: stage tile 0 into buf 0, then advance pointers to tile 1
  gl16(kgA, &lsK0[dA]); gl16(kgB, &lsK0[dB]);
  gl16(vgA, &lsV0[dA]); gl16(vgB, &lsV0[dB]);
  kgA += 4096; kgB += 4096; vgA += 64; vgB += 64;

  auto body = [&](auto curTag, int t) {
    constexpr int CUR = decltype(curTag)::v;
    const u16* lskR = CUR ? lsK1 : lsK0;
    const u16* lsvR = CUR ? lsV1 : lsV0;
    u16* lskW = CUR ? lsK0 : lsK1;
    u16* lsvW = CUR ? lsV0 : lsV1;

    __syncthreads();   // buf[CUR] staged (vmcnt drain); all waves past body t-1

    if (t < 31) {      // stage tile t+1 into the other buffer
      gl16(kgA, &lskW[dA]); gl16(kgB, &lskW[dB]);
      gl16(vgA, &lsvW[dA]); gl16(vgB, &lsvW[dB]);
      kgA += 4096; kgB += 4096; vgA += 64; vgB += 64;
    }

    const u64 mw = *mp; ++mp;                    // 64 mask bits (q=l5, this tile)

    // S' = mfma(K, Qs): frag f covers kv = f*32.. ; lane holds q=l5,
    // kv = f*32 + (r&3) + 8*(r>>2) + 4*h1 per reg r.
    f32x16 s2[2];
    __builtin_amdgcn_s_setprio(1);
#pragma unroll
    for (int f = 0; f < 2; ++f) {
      f32x16 sv = z16;
#pragma unroll
      for (int step = 0; step < 4; ++step) {
        const bf16x8 kf = *(const bf16x8*)&lskR[idx[step] + f * 2048];
        sv = __builtin_amdgcn_mfma_f32_32x32x16_bf16(kf, qf[step], sv, 0, 0, 0);
      }
      s2[f] = sv;
    }
    __builtin_amdgcn_s_setprio(0);

    // softmax numerators p = exp2(S' & m)  (masked -> 1.0) + PV
#pragma unroll
    for (int f = 0; f < 2; ++f) {
      const u32 wf = ((f == 0) ? (u32)mw : (u32)(mw >> 32)) >> h4;
      float p[16];
#pragma unroll
      for (int r = 0; r < 16; ++r) {
        const int pos = (r & 3) + 8 * (r >> 2);
        const int m = sbfe1(wf, pos);            // 0 or -1
        p[r] = fexp2(fmask(s2[f][r], m));
      }
      lp0 += (p[0] + p[4]) + (p[8] + p[12]);
      lp1 += (p[1] + p[5]) + (p[9] + p[13]);
      lp2 += (p[2] + p[6]) + (p[10] + p[14]);
      lp3 += (p[3] + p[7]) + (p[11] + p[15]);
      u32 pk[8];
#pragma unroll
      for (int i = 0; i < 4; ++i) {
        pk[2 * i]     = cvtpk(p[4 * i],     p[4 * i + 1]);
        pk[2 * i + 1] = cvtpk(p[4 * i + 2], p[4 * i + 3]);
      }
      // exchange quads across lane halves: each half gets its 8-contiguous kv run
      plswap(pk[0], pk[2]); plswap(pk[1], pk[3]);   // kv block f*32 + 0..15
      plswap(pk[4], pk[6]); plswap(pk[5], pk[7]);   // kv block f*32 + 16..31

#pragma unroll
      for (int mm = 0; mm < 2; ++mm) {
        const int m = f * 2 + mm;                 // kv 16-block index
        union { u32 u[4]; bf16x8 v; } pu;
        pu.u[0] = pk[4 * mm]; pu.u[1] = pk[4 * mm + 1];
        pu.u[2] = pk[4 * mm + 2]; pu.u[3] = pk[4 * mm + 3];
        __builtin_amdgcn_s_setprio(1);
#pragma unroll
        for (int db = 0; db < 2; ++db) {
          const bf16x8 vf = *(const bf16x8*)&lsvR[idx[m] + db * 2048];
          acc[db] = __builtin_amdgcn_mfma_f32_32x32x16_bf16(vf, pu.v, acc[db], 0, 0, 0);
        }
        __builtin_amdgcn_s_setprio(0);
      }
    }
  };

  for (int tt = 0; tt < 16; ++tt) {
    body(IC<0>{}, 2 * tt);
    body(IC<1>{}, 2 * tt + 1);
  }

  // row sum = own half + partner half (lane l5 <-> l5+32), one rcp per lane
  const float lpart = (lp0 + lp1) + (lp2 + lp3);
  const float tot = lpart + __shfl_xor(lpart, 32, 64);
  const float inv = 1.0f / tot;

  // write O^T: lane (l5,h1) holds O[q=q0+l5][d = db*32 + (r&3)+8*(r>>2)+4*h1]
  u16* orow = x16 + ((size_t)b * 2048 + q0 + l5) * 1024 + h * 64;
#pragma unroll
  for (int db = 0; db < 2; ++db)
#pragma unroll
    for (int r = 0; r < 16; r += 2) {
      const int d = db * 32 + (r & 3) + 8 * (r >> 2) + h4;
      *(u32*)&orow[d] = cvtpk(acc[db][r] * inv, acc[db][r + 1] * inv);
    }
}

// ---------------------------------------------------------------------------
extern "C" void kernel_launch(void* const* d_in, const int* in_sizes, int n_in,
                              void* d_out, int out_size, void* d_ws, size_t ws_size,
                              hipStream_t stream) {
  const float* query = (const float*)d_in[0];
  const float* key   = (const float*)d_in[1];
  const float* value = (const float*)d_in[2];
  const int*   mask  = (const int*)d_in[3];
  const float* Wq = (const float*)d_in[4];
  const float* bq = (const float*)d_in[5];
  const float* Wk = (const float*)d_in[6];
  const float* bk = (const float*)d_in[7];
  const float* Wv = (const float*)d_in[8];
  const float* bv = (const float*)d_in[9];
  const float* Wo = (const float*)d_in[10];
  const float* bo = (const float*)d_in[11];

  char* ws = (char*)d_ws;
  const size_t MB = 1024 * 1024;
  u16* xq   = (u16*)(ws + 0);        // 16MB  [B*S,D] bf16 (later reused as x16)
  u16* xk   = (u16*)(ws + 16 * MB);  // 16MB
  u16* xv   = (u16*)(ws + 32 * MB);  // 16MB
  u16* wq16 = (u16*)(ws + 48 * MB);  // 2MB
  u16* wk16 = (u16*)(ws + 50 * MB);
  u16* wv16 = (u16*)(ws + 52 * MB);
  u16* wo16 = (u16*)(ws + 54 * MB);
  u16* q16  = (u16*)(ws + 56 * MB);  // 16MB [b,h,s,dk] (pre-scaled by log2e/8)
  u16* k16  = (u16*)(ws + 72 * MB);  // 16MB [b,h,s,dk]
  u16* vt16 = (u16*)(ws + 88 * MB);  // 16MB [b,h,dk,s]
  u64* mbits = (u64*)(ws + 104 * MB);// 2MB
  u16* x16  = xq;                    // alias: xq dead before attn writes

  prep_kernel<<<45056, 256, 0, stream>>>(
      (const float4*)query, (const float4*)key, (const float4*)value,
      (const float4*)Wq, (const float4*)Wk, (const float4*)Wv, (const float4*)Wo,
      mask, (us4*)xq, (us4*)xk, (us4*)xv,
      (us4*)wq16, (us4*)wk16, (us4*)wv16, (us4*)wo16, mbits);

  gemm_qkv<<<dim3(64, 8, 3), 256, 0, stream>>>(xq, xk, xv, wq16, wk16, wv16,
                                               bq, bk, bv, q16, k16, vt16);

  attn_kernel<<<dim3(64, 16), 256, 0, stream>>>(q16, k16, vt16, mbits, x16);

  gemm_out<<<dim3(64, 8), 256, 0, stream>>>(x16, wo16, bo, (float*)d_out);
}

// Round 16
// 218.241 us; speedup vs baseline: 1.3848x; 1.0139x over previous
//
#include <hip/hip_runtime.h>

// ---------------------------------------------------------------------------
// MultiHeadedAttention: B=4, S=2048, D=1024, H=16, DK=64
// out = ( softmax( mask_fill( (XqWq^T+bq)(XkWk^T+bk)^T / 8 ) ) (XvWv^T+bv) ) Wo^T + bo
// bf16 MFMA everywhere, f32 accum.
// R16: attn one-tile software pipeline — sm(t-1)+PV(t-1) runs under QK(t)
// (loop was dependency-bound: no pipe >51% with 4 structural levers null).
// Buffer algebra: K[t] in kb[t%2] (staged iter t-1); V[t] in vb[t%2]
// (staged iter t, read by PV(t) in iter t+1; barrier t+1 drains; old
// occupant V[t-2] was read by PV(t-2) in iter t-1, done by barrier t).
// Extra barrier before epilogue drains V[31].
// KNOWN-FREE: attn SQ_LDS_BANK_CONFLICT = 4/b128-read = inherent 2-way
// aliasing (m136: free; R7 proved chasing it regresses).
// XCD map: XCD = linear_block_id % 8 — co-XCD sharers congruent mod 8
// (R8/R9). attn grid (64,16): bh%8 keys heads. GEMMs grid (64,8,*):
// M-tile%8 keys XCD -> A-panels XCD-private.
// R10/R14: bulk memory work stays in dedicated kernels (both fusion modes
// failed). R3: no launch_bounds min-waves beyond natural VGPR step.
// R12: more waves does not fix dependency-bound loops (this round attacks
// the dependency itself).
// ---------------------------------------------------------------------------

typedef __attribute__((ext_vector_type(8))) short bf16x8;    // 4 VGPRs: MFMA A/B frag
typedef __attribute__((ext_vector_type(4))) float f32x4;     // 16x16 C/D frag
typedef __attribute__((ext_vector_type(16))) float f32x16;   // 32x32 C/D frag
typedef __attribute__((ext_vector_type(4))) unsigned short us4;
typedef unsigned long long u64;
typedef unsigned short u16;
typedef unsigned int u32;

#define DEV static __device__ __forceinline__

template <int N> struct IC { static constexpr int v = N; };

DEV u16 f2bf(float f) {                     // RNE f32 -> bf16
  union { float f; unsigned u; } v; v.f = f;
  return (u16)((v.u + 0x7fffu + ((v.u >> 16) & 1u)) >> 16);
}

DEV u32 cvtpk(float lo, float hi) {         // HW RNE pack: [15:0]=bf16(lo),[31:16]=bf16(hi)
  u32 r;
  asm("v_cvt_pk_bf16_f32 %0, %1, %2" : "=v"(r) : "v"(lo), "v"(hi));
  return r;
}

// v_permlane32_swap_b32 x, y:  x' = [x_lo32 | y_lo32], y' = [x_hi32 | y_hi32]
DEV void plswap(u32& x, u32& y) {
  asm("v_permlane32_swap_b32 %0, %1" : "+v"(x), "+v"(y));
}

// raw v_exp_f32 (2^x): OCML exp2f adds range handling we don't need
DEV float fexp2(float x) {
#if __has_builtin(__builtin_amdgcn_exp2f)
  return __builtin_amdgcn_exp2f(x);
#else
  float r;
  asm volatile("v_exp_f32 %0, %1\n\ts_nop 1" : "=v"(r) : "v"(x));
  return r;
#endif
}

DEV int sbfe1(u32 w, int pos) {             // sign-extended 1-bit field: 0 or -1
#if __has_builtin(__builtin_amdgcn_sbfe)
  return __builtin_amdgcn_sbfe((int)w, pos, 1);
#else
  return ((int)(w << (31 - pos))) >> 31;
#endif
}

DEV float fmask(float s, int m) {           // s if m==-1 else 0.0f (bitwise and)
  union { float f; int i; } u; u.f = s; u.i &= m; return u.f;
}

DEV void gl16(const u16* g, u16* l) {       // async global->LDS, 16B/lane
  __builtin_amdgcn_global_load_lds(
      (const __attribute__((address_space(1))) unsigned int*)g,
      (__attribute__((address_space(3))) unsigned int*)l, 16, 0, 0);
}

// XOR swizzle (involution): spreads 16B slots across banks. Used on BOTH the
// pre-swizzled global source (staging) and the ds_read side (rule #21).
DEV int swz(int row, int slot) { return slot ^ (row & 7); }

// ---------------------------------------------------------------------------
// Fused prep: f32->bf16 converts (q/k/v + 4 weights) and mask bit-pack.
// Mask region: 16384 blocks x 4 INDEPENDENT rounds (4x per-wave MLP).
// ---------------------------------------------------------------------------
__global__ void prep_kernel(const float4* __restrict__ q, const float4* __restrict__ k,
                            const float4* __restrict__ v, const float4* __restrict__ wq,
                            const float4* __restrict__ wk, const float4* __restrict__ wv,
                            const float4* __restrict__ wo, const int* __restrict__ mask,
                            us4* __restrict__ xq, us4* __restrict__ xk, us4* __restrict__ xv,
                            us4* __restrict__ owq, us4* __restrict__ owk,
                            us4* __restrict__ owv, us4* __restrict__ owo,
                            u64* __restrict__ bits) {
  const int bid = blockIdx.x;
  if (bid < 28672) {                       // convert regions
    const float4* src; us4* dst; int base;
    if (bid < 8192)       { src = q;  dst = xq;  base = 0; }
    else if (bid < 16384) { src = k;  dst = xk;  base = 8192; }
    else if (bid < 24576) { src = v;  dst = xv;  base = 16384; }
    else if (bid < 25600) { src = wq; dst = owq; base = 24576; }
    else if (bid < 26624) { src = wk; dst = owk; base = 25600; }
    else if (bid < 27648) { src = wv; dst = owv; base = 26624; }
    else                  { src = wo; dst = owo; base = 27648; }
    const int i = (bid - base) * 256 + threadIdx.x;
    const float4 t = src[i];
    us4 r = {f2bf(t.x), f2bf(t.y), f2bf(t.z), f2bf(t.w)};
    dst[i] = r;
  } else {                                 // mask pack: 16384 blocks x 4 rounds
    const int base = (bid - 28672) * 1024 + threadIdx.x;
    int mv[4];
#pragma unroll
    for (int kk = 0; kk < 4; ++kk) mv[kk] = mask[base + kk * 256];  // 4 loads in flight
#pragma unroll
    for (int kk = 0; kk < 4; ++kk) {
      const u64 bm = __ballot(mv[kk] != 0);
      if ((threadIdx.x & 63) == 0) bits[(base + kk * 256) >> 6] = bm;
    }
  }
}

// ---------------------------------------------------------------------------
// GEMM body: D[pr][qr] = sum_k P[pr][k]*Q[qr][k]  (+bias), both K-major.
// 128x128 tile, BK=64, 4 waves (2x2), wave=64x64 out = 4x4 frags of 16x16x32.
// MODE 0: out bf16 [b,h,s,dk] ; MODE 1: out bf16 [b,h,dk,s] (V^T) ;
// MODE 2: out f32 [m,n] ; MODE 3: like 0 but scaled by log2(e)/8 (Q proj).
// ---------------------------------------------------------------------------
template <int MODE>
DEV void gemm_body(const u16* __restrict__ P, const u16* __restrict__ Q,
                   const float* __restrict__ bias, void* __restrict__ outp,
                   int pr0, int qr0, u16* lsP, u16* lsQ) {
  constexpr int K = 1024;
  const int tid = threadIdx.x;
  const int w = tid >> 6, lane = tid & 63;
  const int wm = w >> 1, wn = w & 1;
  const int lo = lane & 15, hi = lane >> 4;
  const int srow = lane >> 3, sslot = lane & 7;   // staging: 8 rows x 8 slots / 1KB chunk

  f32x4 acc[4][4];
#pragma unroll
  for (int i = 0; i < 4; ++i)
#pragma unroll
    for (int j = 0; j < 4; ++j) acc[i][j] = (f32x4){0.f, 0.f, 0.f, 0.f};

  for (int kt = 0; kt < K; kt += 64) {
#pragma unroll
    for (int j = 0; j < 4; ++j) {
      const int c = w * 4 + j;
      const int row = c * 8 + srow;
      const int gs = swz(row, sslot);           // pre-swizzled global source
      gl16(P + (pr0 + row) * K + kt + gs * 8, &lsP[c * 512]);
      gl16(Q + (qr0 + row) * K + kt + gs * 8, &lsQ[c * 512]);
    }
    __syncthreads();   // drains vmcnt before barrier
#pragma unroll
    for (int kk = 0; kk < 2; ++kk) {
      bf16x8 af[4], bfr[4];
#pragma unroll
      for (int mf = 0; mf < 4; ++mf) {
        const int r = wm * 64 + mf * 16 + lo;
        af[mf] = *(const bf16x8*)&lsP[r * 64 + swz(r, kk * 4 + hi) * 8];
      }
#pragma unroll
      for (int nf = 0; nf < 4; ++nf) {
        const int r = wn * 64 + nf * 16 + lo;
        bfr[nf] = *(const bf16x8*)&lsQ[r * 64 + swz(r, kk * 4 + hi) * 8];
      }
#pragma unroll
      for (int mf = 0; mf < 4; ++mf)
#pragma unroll
        for (int nf = 0; nf < 4; ++nf)
          acc[mf][nf] = __builtin_amdgcn_mfma_f32_16x16x32_bf16(af[mf], bfr[nf], acc[mf][nf], 0, 0, 0);
    }
    __syncthreads();
  }

#pragma unroll
  for (int mf = 0; mf < 4; ++mf) {
#pragma unroll
    for (int nf = 0; nf < 4; ++nf) {
#pragma unroll
      for (int i = 0; i < 4; ++i) {
        const int gm = pr0 + wm * 64 + mf * 16 + hi * 4 + i;
        const int gn = qr0 + wn * 64 + nf * 16 + lo;
        float val = acc[mf][nf][i];
        if constexpr (MODE == 0 || MODE == 3) {  // [b,h,s,dk] bf16 (K / scaled Q)
          val += bias[gn];
          if constexpr (MODE == 3) val *= 0.18033688011112042f;  // log2(e)/8
          const int b = gm >> 11, s = gm & 2047, h = gn >> 6, dk = gn & 63;
          ((u16*)outp)[(((b * 16 + h) * 2048 + s) * 64) + dk] = f2bf(val);
        } else if constexpr (MODE == 1) { // [b,h,dk,s] bf16 (V^T)
          val += bias[gm];
          const int h = gm >> 6, dk = gm & 63, b = gn >> 11, s = gn & 2047;
          ((u16*)outp)[(((b * 16 + h) * 64 + dk) * 2048) + s] = f2bf(val);
        } else {                          // f32 [m,n]
          val += bias[gn];
          ((float*)outp)[(size_t)gm * 1024 + gn] = val;
        }
      }
    }
  }
}

// fused Q/K/V projections, grid (64, 8, 3): x = M-tile (XCD key: A-panels
// XCD-private, fetched once; 2MB B replicated per XCD), y = N-tile.
// z=0 -> scaled Q proj, z=1 -> K proj, z=2 -> V proj (writes V^T).
__launch_bounds__(256)
__global__ void gemm_qkv(const u16* __restrict__ xq, const u16* __restrict__ xk,
                         const u16* __restrict__ xv, const u16* __restrict__ wq,
                         const u16* __restrict__ wk, const u16* __restrict__ wv,
                         const float* __restrict__ bq, const float* __restrict__ bk,
                         const float* __restrict__ bv, u16* __restrict__ q16,
                         u16* __restrict__ k16, u16* __restrict__ vt16) {
  __shared__ u16 lsP[128 * 64];
  __shared__ u16 lsQ[128 * 64];
  const int z = blockIdx.z;
  if (z == 0)      gemm_body<3>(xq, wq, bq, q16,  blockIdx.x * 128, blockIdx.y * 128, lsP, lsQ);
  else if (z == 1) gemm_body<0>(xk, wk, bk, k16,  blockIdx.x * 128, blockIdx.y * 128, lsP, lsQ);
  else             gemm_body<1>(wv, xv, bv, vt16, blockIdx.y * 128, blockIdx.x * 128, lsP, lsQ);
}

// grid (64, 8): x = M-tile (XCD key), y = N-tile
__launch_bounds__(256)
__global__ void gemm_out(const u16* __restrict__ P, const u16* __restrict__ Q,
                         const float* __restrict__ bias, float* __restrict__ outp) {
  __shared__ u16 lsP[128 * 64];
  __shared__ u16 lsQ[128 * 64];
  gemm_body<2>(P, Q, bias, outp, blockIdx.x * 128, blockIdx.y * 128, lsP, lsQ);
}

// ---------------------------------------------------------------------------
// Flash attention, one-tile software pipeline. grid=(B*H, S/128).
// 256 thr = 4 waves, wave owns 32 q-rows. 32x32x16 MFMA, swapped operands:
// S' = mfma(K,Qs), Qs pre-scaled log2(e)/8; p = exp2(S' & mask) (masked ->
// 1.0 == TINY fill). P in regs via cvt_pk + v_permlane32_swap; O^T=mfma(V,P).
// Pipeline per iter t: barrier -> stage K[t+1]->kb[(t+1)%2], V[t]->vb[t%2]
// -> sm(t-1)+PV(t-1) (reads vb[(t-1)%2], scores from sOld regs) -> QK(t)
// into sOld. sm VALU fills QK/ds shadows; QK latency drains over barrier.
// ---------------------------------------------------------------------------
__launch_bounds__(256, 4)
__global__ void attn_kernel(const u16* __restrict__ q16, const u16* __restrict__ k16,
                            const u16* __restrict__ vt16, const u64* __restrict__ mb,
                            u16* __restrict__ x16) {
  __shared__ u16 lsK0[64 * 64], lsK1[64 * 64];   // K[even]/K[odd], swizzled, 8KB each
  __shared__ u16 lsV0[64 * 64], lsV1[64 * 64];   // V[even]/V[odd], swizzled, 8KB each
  const int bh = blockIdx.x;
  const int b = bh >> 4, h = bh & 15;
  const int w = threadIdx.x >> 6, lane = threadIdx.x & 63;
  const int l5 = lane & 31, h1 = lane >> 5, l7 = l5 & 7;
  const int h4 = h1 * 4;
  const int q0 = blockIdx.y * 128 + w * 32;
  const u16* qbase = q16 + (size_t)bh * 2048 * 64;
  const u16* kbase = k16 + (size_t)bh * 2048 * 64;
  const u16* vbase = vt16 + (size_t)bh * 64 * 2048;
  const u64* mp = mb + ((size_t)b * 2048 + q0 + l5) * 32;   // this lane's q-row

  // per-lane constant LDS read offsets (u16 units); f/db add 2048 via imm
  int idx[4];
#pragma unroll
  for (int s4 = 0; s4 < 4; ++s4)
    idx[s4] = l5 * 64 + (((s4 * 2 + h1) ^ l7) * 8);

  // staging geometry: chunks cA=2w (rowA), cB=2w+1 (rowB=rowA+8); shared gs
  const int srow = lane >> 3, sslot = lane & 7;
  const int gs = (sslot ^ srow) * 8;             // row&7 == srow for both chunks
  const int rowA = w * 16 + srow;
  const int dA = w * 1024, dB = w * 1024 + 512;  // LDS chunk dests (u16 units)
  const u16* kgA = kbase + rowA * 64 + gs;       // K chunk A; B = +512 elems (1KB imm)
  const u16* vgA = vbase + rowA * 2048 + gs;     // V chunk A; walk +64/tile
  const u16* vgB = vbase + (rowA + 8) * 2048 + gs;

  const f32x16 z16 = (f32x16)(0.f);

  // Q frags (B-operand): lane holds Qs[q0+l5][step*16 + h1*8 .. +8]
  bf16x8 qf[4];
#pragma unroll
  for (int step = 0; step < 4; ++step)
    qf[step] = *(const bf16x8*)&qbase[(q0 + l5) * 64 + step * 16 + h1 * 8];

  f32x16 acc[2];                                 // O^T frags: d-blocks 0,1
  acc[0] = z16; acc[1] = z16;
  f32x16 sOld[2];                                // pipelined scores (tile t-1)
  u64 mwOld = 0;                                 // pipelined mask bits
  float lp0 = 0.f, lp1 = 0.f;                    // 2-way split row-sum chains

  // softmax(t-1) + PV(t-1): consumes sOld/mwOld, accumulates acc/lp
  auto sm_pv = [&](const u16* lsvR) {
#pragma unroll
    for (int f = 0; f < 2; ++f) {
      const u32 wf = ((f == 0) ? (u32)mwOld : (u32)(mwOld >> 32)) >> h4;
      float p[16];
#pragma unroll
      for (int r = 0; r < 16; ++r) {
        const int pos = (r & 3) + 8 * (r >> 2);
        const int m = sbfe1(wf, pos);            // 0 or -1
        p[r] = fexp2(fmask(sOld[f][r], m));      // masked -> exp2(0)=1 (TINY fill)
      }
      lp0 += ((p[0] + p[4]) + (p[8] + p[12])) + ((p[2] + p[6]) + (p[10] + p[14]));
      lp1 += ((p[1] + p[5]) + (p[9] + p[13])) + ((p[3] + p[7]) + (p[11] + p[15]));
      u32 pk[8];
#pragma unroll
      for (int i = 0; i < 4; ++i) {
        pk[2 * i]     = cvtpk(p[4 * i],     p[4 * i + 1]);
        pk[2 * i + 1] = cvtpk(p[4 * i + 2], p[4 * i + 3]);
      }
      // exchange quads across lane halves: each half gets its 8-contiguous kv run
      plswap(pk[0], pk[2]); plswap(pk[1], pk[3]);   // kv block f*32 + 0..15
      plswap(pk[4], pk[6]); plswap(pk[5], pk[7]);   // kv block f*32 + 16..31

#pragma unroll
      for (int mm = 0; mm < 2; ++mm) {
        const int m = f * 2 + mm;                 // kv 16-block index
        union { u32 u[4]; bf16x8 v; } pu;
        pu.u[0] = pk[4 * mm]; pu.u[1] = pk[4 * mm + 1];
        pu.u[2] = pk[4 * mm + 2]; pu.u[3] = pk[4 * mm + 3];
        __builtin_amdgcn_s_setprio(1);
#pragma unroll
        for (int db = 0; db < 2; ++db) {
          const bf16x8 vf = *(const bf16x8*)&lsvR[idx[m] + db * 2048];
          acc[db] = __builtin_amdgcn_mfma_f32_32x32x16_bf16(vf, pu.v, acc[db], 0, 0, 0);
        }
        __builtin_amdgcn_s_setprio(0);
      }
    }
  };

  // prologue: stage K[0] -> lsK0 only (V[0] staged inside iter 0)
  gl16(kgA, &lsK0[dA]); gl16(kgA + 512, &lsK0[dB]);
  kgA += 4096;

  auto body = [&](auto curTag, int t) {
    constexpr int CUR = decltype(curTag)::v;     // CUR = t%2
    const u16* lskR = CUR ? lsK1 : lsK0;         // K[t]
    u16* lskW = CUR ? lsK0 : lsK1;               // K[t+1] dest
    u16* lsvW = CUR ? lsV1 : lsV0;               // V[t] dest
    const u16* lsvR = CUR ? lsV0 : lsV1;         // V[t-1]

    __syncthreads();   // K[t],V[t-1] staged (vmcnt drain); all waves past iter t-1

    if (t < 31) {      // stage K[t+1]
      gl16(kgA, &lskW[dA]); gl16(kgA + 512, &lskW[dB]);
      kgA += 4096;
    }
    // stage V[t] (read by PV(t) next iter; old occupant dead since barrier)
    gl16(vgA, &lsvW[dA]); gl16(vgB, &lsvW[dB]);
    vgA += 64; vgB += 64;

    const u64 mwNew = *mp; ++mp;                 // mask bits for tile t

    if (t > 0) sm_pv(lsvR);                      // finish tile t-1 under QK(t)
    mwOld = mwNew;

    // QK(t): S' = mfma(K, Qs) into sOld (regs freed by sm_pv above)
    __builtin_amdgcn_s_setprio(1);
#pragma unroll
    for (int f = 0; f < 2; ++f) {
      f32x16 sv = z16;
#pragma unroll
      for (int step = 0; step < 4; ++step) {
        const bf16x8 kf = *(const bf16x8*)&lskR[idx[step] + f * 2048];
        sv = __builtin_amdgcn_mfma_f32_32x32x16_bf16(kf, qf[step], sv, 0, 0, 0);
      }
      sOld[f] = sv;
    }
    __builtin_amdgcn_s_setprio(0);
  };

  for (int tt = 0; tt < 16; ++tt) {
    body(IC<0>{}, 2 * tt);
    body(IC<1>{}, 2 * tt + 1);
  }

  // epilogue: V[31] staged during iter 31 -> drain before final PV
  __syncthreads();
  sm_pv(lsV1);                                   // tile 31 (31%2 = 1)

  // row sum = own half + partner half (lane l5 <-> l5+32), one rcp per lane
  const float lpart = lp0 + lp1;
  const float tot = lpart + __shfl_xor(lpart, 32, 64);
  const float inv = 1.0f / tot;

  // write O^T: lane (l5,h1) holds O[q=q0+l5][d = db*32 + (r&3)+8*(r>>2)+4*h1]
  u16* orow = x16 + ((size_t)b * 2048 + q0 + l5) * 1024 + h * 64;
#pragma unroll
  for (int db = 0; db < 2; ++db)
#pragma unroll
    for (int r = 0; r < 16; r += 2) {
      const int d = db * 32 + (r & 3) + 8 * (r >> 2) + h4;
      *(u32*)&orow[d] = cvtpk(acc[db][r] * inv, acc[db][r + 1] * inv);
    }
}

// ---------------------------------------------------------------------------
extern "C" void kernel_launch(void* const* d_in, const int* in_sizes, int n_in,
                              void* d_out, int out_size, void* d_ws, size_t ws_size,
                              hipStream_t stream) {
  const float* query = (const float*)d_in[0];
  const float* key   = (const float*)d_in[1];
  const float* value = (const float*)d_in[2];
  const int*   mask  = (const int*)d_in[3];
  const float* Wq = (const float*)d_in[4];
  const float* bq = (const float*)d_in[5];
  const float* Wk = (const float*)d_in[6];
  const float* bk = (const float*)d_in[7];
  const float* Wv = (const float*)d_in[8];
  const float* bv = (const float*)d_in[9];
  const float* Wo = (const float*)d_in[10];
  const float* bo = (const float*)d_in[11];

  char* ws = (char*)d_ws;
  const size_t MB = 1024 * 1024;
  u16* xq   = (u16*)(ws + 0);        // 16MB  [B*S,D] bf16 (later reused as x16)
  u16* xk   = (u16*)(ws + 16 * MB);  // 16MB
  u16* xv   = (u16*)(ws + 32 * MB);  // 16MB
  u16* wq16 = (u16*)(ws + 48 * MB);  // 2MB
  u16* wk16 = (u16*)(ws + 50 * MB);
  u16* wv16 = (u16*)(ws + 52 * MB);
  u16* wo16 = (u16*)(ws + 54 * MB);
  u16* q16  = (u16*)(ws + 56 * MB);  // 16MB [b,h,s,dk] (pre-scaled by log2e/8)
  u16* k16  = (u16*)(ws + 72 * MB);  // 16MB [b,h,s,dk]
  u16* vt16 = (u16*)(ws + 88 * MB);  // 16MB [b,h,dk,s]
  u64* mbits = (u64*)(ws + 104 * MB);// 2MB
  u16* x16  = xq;                    // alias: xq dead before attn writes

  prep_kernel<<<45056, 256, 0, stream>>>(
      (const float4*)query, (const float4*)key, (const float4*)value,
      (const float4*)Wq, (const float4*)Wk, (const float4*)Wv, (const float4*)Wo,
      mask, (us4*)xq, (us4*)xk, (us4*)xv,
      (us4*)wq16, (us4*)wk16, (us4*)wv16, (us4*)wo16, mbits);

  gemm_qkv<<<dim3(64, 8, 3), 256, 0, stream>>>(xq, xk, xv, wq16, wk16, wv16,
                                               bq, bk, bv, q16, k16, vt16);

  attn_kernel<<<dim3(64, 16), 256, 0, stream>>>(q16, k16, vt16, mbits, x16);

  gemm_out<<<dim3(64, 8), 256, 0, stream>>>(x16, wo16, bo, (float*)d_out);
}